// Round 4
// baseline (2412.503 us; speedup 1.0000x reference)
//
#include <hip/hip_runtime.h>
#include <stdint.h>

#define ROT(x, r) __builtin_rotateleft32((uint32_t)(x), (r))

// Threefry-2x32, 20 rounds
#define TF_G1(x0, x1) \
  x0 += x1; x1 = ROT(x1, 13); x1 ^= x0; \
  x0 += x1; x1 = ROT(x1, 15); x1 ^= x0; \
  x0 += x1; x1 = ROT(x1, 26); x1 ^= x0; \
  x0 += x1; x1 = ROT(x1, 6);  x1 ^= x0;

#define TF_G2(x0, x1) \
  x0 += x1; x1 = ROT(x1, 17); x1 ^= x0; \
  x0 += x1; x1 = ROT(x1, 29); x1 ^= x0; \
  x0 += x1; x1 = ROT(x1, 16); x1 ^= x0; \
  x0 += x1; x1 = ROT(x1, 24); x1 ^= x0;

__device__ __forceinline__ void threefry_full(uint32_t k0, uint32_t k1,
                                              uint32_t c0, uint32_t c1,
                                              uint32_t& o0, uint32_t& o1) {
  uint32_t ks2 = k0 ^ k1 ^ 0x1BD11BDAu;
  uint32_t x0 = c0 + k0, x1 = c1 + k1;
  TF_G1(x0, x1); x0 += k1;  x1 += ks2 + 1u;
  TF_G2(x0, x1); x0 += ks2; x1 += k0 + 2u;
  TF_G1(x0, x1); x0 += k0;  x1 += k1 + 3u;
  TF_G2(x0, x1); x0 += k1;  x1 += ks2 + 4u;
  TF_G1(x0, x1); x0 += ks2; x1 += k0 + 5u;
  o0 = x0; o1 = x1;
}

__device__ __forceinline__ uint32_t tf_bits(uint32_t k0, uint32_t k1, uint32_t ks2,
                                            uint32_t cnt) {
  uint32_t x0 = k0, x1 = cnt + k1;
  TF_G1(x0, x1); x0 += k1;  x1 += ks2 + 1u;
  TF_G2(x0, x1); x0 += ks2; x1 += k0 + 2u;
  TF_G1(x0, x1); x0 += k0;  x1 += k1 + 3u;
  TF_G2(x0, x1); x0 += k1;  x1 += ks2 + 4u;
  TF_G1(x0, x1); x0 += ks2; x1 += k0 + 5u;
  return x0 ^ x1;
}

// ---- 4-stream interleaved threefry (used by fallback scalar path) ----
#define SR4(r) \
  a0 += a1; a1 = ROT(a1, r); a1 ^= a0; \
  b0 += b1; b1 = ROT(b1, r); b1 ^= b0; \
  c0 += c1; c1 = ROT(c1, r); c1 ^= c0; \
  d0 += d1; d1 = ROT(d1, r); d1 ^= d0;

#define INJ4(p, q) \
  a0 += (p); a1 += (q); \
  b0 += (p); b1 += (q); \
  c0 += (p); c1 += (q); \
  d0 += (p); d1 += (q);

__device__ __forceinline__ void tf_bits4(uint32_t k0, uint32_t k1, uint32_t ks2,
                                         uint32_t ca, uint32_t cb, uint32_t cc,
                                         uint32_t cd, uint32_t& ra, uint32_t& rb,
                                         uint32_t& rc, uint32_t& rd) {
  uint32_t a0 = k0, a1 = ca + k1;
  uint32_t b0 = k0, b1 = cb + k1;
  uint32_t c0 = k0, c1 = cc + k1;
  uint32_t d0 = k0, d1 = cd + k1;
  SR4(13) SR4(15) SR4(26) SR4(6)
  INJ4(k1, ks2 + 1u)
  SR4(17) SR4(29) SR4(16) SR4(24)
  INJ4(ks2, k0 + 2u)
  SR4(13) SR4(15) SR4(26) SR4(6)
  INJ4(k0, k1 + 3u)
  SR4(17) SR4(29) SR4(16) SR4(24)
  INJ4(k1, ks2 + 4u)
  SR4(13) SR4(15) SR4(26) SR4(6)
  INJ4(ks2, k0 + 5u)
  ra = a0 ^ a1; rb = b0 ^ b1; rc = c0 ^ c1; rd = d0 ^ d1;
}

// ---- 8-stream interleaved threefry (ILP=8; init mov+add folded) ----
#define SR8(r) \
  a0 += a1; a1 = ROT(a1, r); a1 ^= a0; \
  b0 += b1; b1 = ROT(b1, r); b1 ^= b0; \
  c0 += c1; c1 = ROT(c1, r); c1 ^= c0; \
  d0 += d1; d1 = ROT(d1, r); d1 ^= d0; \
  e0 += e1; e1 = ROT(e1, r); e1 ^= e0; \
  f0 += f1; f1 = ROT(f1, r); f1 ^= f0; \
  g0 += g1; g1 = ROT(g1, r); g1 ^= g0; \
  h0 += h1; h1 = ROT(h1, r); h1 ^= h0;

#define INJ8(p, q) \
  a0 += (p); a1 += (q); \
  b0 += (p); b1 += (q); \
  c0 += (p); c1 += (q); \
  d0 += (p); d1 += (q); \
  e0 += (p); e1 += (q); \
  f0 += (p); f1 += (q); \
  g0 += (p); g1 += (q); \
  h0 += (p); h1 += (q);

// cks = cbase + k1 + 16*s  (per-lane); stream e's counter = cbase + 16*s + e.
// Round-1's "x0 += x1" is folded into the x0 init (x0 = k0 + x1), and the
// x1 init "c + k1" is folded into cks — saves mov + 2 adds per draw.
__device__ __forceinline__ void tf_bits8(uint32_t k0, uint32_t k1, uint32_t ks2,
                                         uint32_t cks,
                                         uint32_t& r0, uint32_t& r1, uint32_t& r2,
                                         uint32_t& r3, uint32_t& r4, uint32_t& r5,
                                         uint32_t& r6, uint32_t& r7) {
  uint32_t a1 = cks;      uint32_t a0 = a1 + k0;
  uint32_t b1 = cks + 1u; uint32_t b0 = b1 + k0;
  uint32_t c1 = cks + 2u; uint32_t c0 = c1 + k0;
  uint32_t d1 = cks + 3u; uint32_t d0 = d1 + k0;
  uint32_t e1 = cks + 4u; uint32_t e0 = e1 + k0;
  uint32_t f1 = cks + 5u; uint32_t f0 = f1 + k0;
  uint32_t g1 = cks + 6u; uint32_t g0 = g1 + k0;
  uint32_t h1 = cks + 7u; uint32_t h0 = h1 + k0;
  // round 1 (add already folded into init): rot13 + xor only
  a1 = ROT(a1, 13); a1 ^= a0;
  b1 = ROT(b1, 13); b1 ^= b0;
  c1 = ROT(c1, 13); c1 ^= c0;
  d1 = ROT(d1, 13); d1 ^= d0;
  e1 = ROT(e1, 13); e1 ^= e0;
  f1 = ROT(f1, 13); f1 ^= f0;
  g1 = ROT(g1, 13); g1 ^= g0;
  h1 = ROT(h1, 13); h1 ^= h0;
  SR8(15) SR8(26) SR8(6)
  INJ8(k1, ks2 + 1u)
  SR8(17) SR8(29) SR8(16) SR8(24)
  INJ8(ks2, k0 + 2u)
  SR8(13) SR8(15) SR8(26) SR8(6)
  INJ8(k0, k1 + 3u)
  SR8(17) SR8(29) SR8(16) SR8(24)
  INJ8(k1, ks2 + 4u)
  SR8(13) SR8(15) SR8(26) SR8(6)
  INJ8(ks2, k0 + 5u)
  r0 = a0 ^ a1; r1 = b0 ^ b1; r2 = c0 ^ c1; r3 = d0 ^ d1;
  r4 = e0 ^ e1; r5 = f0 ^ f1; r6 = g0 ^ g1; r7 = h0 ^ h1;
}

typedef __attribute__((ext_vector_type(8))) short bhalf8;   // 8 bf16 (4 VGPR)
typedef __attribute__((ext_vector_type(16))) float fx16;    // 16 f32 acc

static __device__ __forceinline__ uint16_t f2bf_rne(float f) {
  uint32_t u = __float_as_uint(f);
  uint32_t r = (u + 0x7FFFu + ((u >> 16) & 1u)) >> 16;
  return (uint16_t)r;
}

// Exact threshold: u = (bits>>9)*2^-23 < x  <=>  bits>>9 < ceil(x*2^23)
// x*8388608.0f is EXACT in fp32. Saturate at k==2^23: always-spike.
static __device__ __forceinline__ uint32_t thr_from_x(float x) {
  const float xf = x * 8388608.0f;
  uint32_t k = (uint32_t)xf;
  k += ((float)k < xf) ? 1u : 0u;                 // ceil
  return (k >= 8388608u) ? 0xFFFFFFFFu : (k << 9);
}

__global__ __launch_bounds__(256)
void prep_thr(const float* __restrict__ x, uint32_t* __restrict__ thr) {
  int i = blockIdx.x * 256 + threadIdx.x;
  if (i >= 16384 * 784) return;
  thr[i] = thr_from_x(x[i]);
}

// WT[j][0..15]: W[o][j] for o<10, pad 0 — 64 B/row (old scalar-FMA path)
__global__ __launch_bounds__(256)
void prep_wt(const float* __restrict__ W, float* __restrict__ WT) {
  int i = blockIdx.x * 256 + threadIdx.x;
  if (i >= 784 * 16) return;
  int j = i >> 4, o = i & 15;
  WT[i] = (o < 10) ? W[o * 784 + j] : 0.0f;
}

// ---------- split-bf16 B-fragments for mfma_f32_32x32x16_bf16 ----------
// B tile at K-step s (K=16, N=32): lane l holds col = l&31, k = (l>>5)*8 + e.
// Layout: WB[((s*2 + h)*64 + l)*8 + e], h=0 hi, h=1 lo.  49*2*64*8 u16 = 98 KB.
// W = hi + lo (both bf16): products s*hi, s*lo exact (s in {0,1}) -> fp32-class.
__global__ __launch_bounds__(256)
void prep_wb(const float* __restrict__ W, uint16_t* __restrict__ WB) {
  int idx = blockIdx.x * 256 + threadIdx.x;   // (s*2+h)*64 + l
  if (idx >= 49 * 2 * 64) return;
  int l = idx & 63;
  int sh = idx >> 6;
  int h = sh & 1;
  int s = sh >> 1;
  int o = l & 31;
  int kg = l >> 5;
  for (int e = 0; e < 8; ++e) {
    int j = s * 16 + kg * 8 + e;
    float w = (o < 10) ? W[o * 784 + j] : 0.0f;
    uint16_t hi = f2bf_rne(w);
    float whi = __uint_as_float((uint32_t)hi << 16);
    float lo = w - whi;                        // exact residual in fp32
    WB[(size_t)idx * 8 + e] = h ? f2bf_rne(lo) : hi;
  }
}

// ---------- phase 1 (MFMA): one wave = 32 rows x one t; K=784 = 49 x 16 ----
// Same body as round 3 (95% of 4-cyc-int-model ceiling). Single change:
// 1024-thread blocks (16 waves/WG, 2 WG/CU = 32 waves/CU) — occupancy probe
// to discriminate the 4-cyc vs 2-cyc int-VALU cadence model.
__global__ __launch_bounds__(1024, 8)
void snn_phase1m(const uint32_t* __restrict__ thrg,
                 const uint16_t* __restrict__ WB,
                 float* __restrict__ Iws) {
  const uint32_t wid = (blockIdx.x * 1024u + (uint32_t)threadIdx.x) >> 6;  // < 51200
  const uint32_t lane = (uint32_t)threadIdx.x & 63u;
  const uint32_t rowtile = wid / 100u;          // 0..511
  const uint32_t t = wid - rowtile * 100u;      // 0..99
  const uint32_t o = lane & 31u;                // A row / C col within tile
  const uint32_t kg = lane >> 5;                // k-group 0/1
  const uint32_t r = rowtile * 32u + o;         // global batch row

  // per-t step key (matches jax.random.split(key(42),100)[t], partitionable)
  uint32_t k0, k1;
  threefry_full(0u, 42u, 0u, t, k0, k1);
  const uint32_t ks2 = k0 ^ k1 ^ 0x1BD11BDAu;
  const uint32_t cbase = r * 784u + kg * 8u;    // counter/thr base for e=0
  const uint32_t ck = cbase + k1;               // fold +k1 once

  const uint32_t* ta = thrg + cbase;            // 16B-aligned
  const uint16_t* wb = WB + (size_t)lane * 8u;

  fx16 acc;
#pragma unroll
  for (int i = 0; i < 16; ++i) acc[i] = 0.0f;

#pragma unroll 2
  for (uint32_t s = 0; s < 49u; ++s) {
    // thresholds for this lane's 8 draws (2 x dwordx4)
    const uint4 tv0 = *(const uint4*)(ta + (s << 4));
    const uint4 tv1 = *(const uint4*)(ta + (s << 4) + 4u);
    // split-bf16 W fragments (same cachelines for every wave -> L1/L2 hit)
    const bhalf8 bhi = *(const bhalf8*)(wb + (size_t)s * 1024u);
    const bhalf8 blo = *(const bhalf8*)(wb + (size_t)s * 1024u + 512u);

    uint32_t b0, b1, b2, b3, b4, b5, b6, b7;
    tf_bits8(k0, k1, ks2, ck + (s << 4), b0, b1, b2, b3, b4, b5, b6, b7);

    // pack spikes as bf16 {1.0, 0.0} pairs: low half = even k
    union { uint32_t u[4]; bhalf8 v; } A;
    A.u[0] = (b0 < tv0.x ? 0x3F80u : 0u) | (b1 < tv0.y ? 0x3F800000u : 0u);
    A.u[1] = (b2 < tv0.z ? 0x3F80u : 0u) | (b3 < tv0.w ? 0x3F800000u : 0u);
    A.u[2] = (b4 < tv1.x ? 0x3F80u : 0u) | (b5 < tv1.y ? 0x3F800000u : 0u);
    A.u[3] = (b6 < tv1.z ? 0x3F80u : 0u) | (b7 < tv1.w ? 0x3F800000u : 0u);

    acc = __builtin_amdgcn_mfma_f32_32x32x16_bf16(A.v, bhi, acc, 0, 0, 0);
    acc = __builtin_amdgcn_mfma_f32_32x32x16_bf16(A.v, blo, acc, 0, 0, 0);
  }

  // C/D: col = lane&31, row = (reg&3) + 8*(reg>>2) + 4*(lane>>5)  [m74/m101]
  if (o < 10u) {
    float* dst = Iws + (size_t)(rowtile * 32u + kg * 4u) * 1000u + t * 10u + o;
#pragma unroll
    for (int reg = 0; reg < 16; ++reg) {
      const uint32_t row_l = (uint32_t)((reg & 3) + 8 * (reg >> 2));
      dst[(size_t)row_l * 1000u] = acc[reg];
    }
  }
}

// ---------- phase 1 (old scalar-FMA path, kept as ws fallback) ----------
template <bool USE_THR>
__global__ __launch_bounds__(256, 8)
void snn_phase1(const float* __restrict__ x, const uint32_t* __restrict__ thrg,
                const float* __restrict__ WT, float* __restrict__ Iws) {
  const uint32_t task = blockIdx.x * 256u + (uint32_t)threadIdx.x;
  const uint32_t row = task / 100u;
  const uint32_t t = task - row * 100u;

  uint32_t k0, k1;
  threefry_full(0u, 42u, 0u, t, k0, k1);
  const uint32_t ks2 = k0 ^ k1 ^ 0x1BD11BDAu;
  const uint32_t cnt0 = row * 784u;

  const uint32_t* trow = thrg + cnt0;
  const float* xrow = x + cnt0;

  float I0 = 0, I1 = 0, I2 = 0, I3 = 0, I4 = 0,
        I5 = 0, I6 = 0, I7 = 0, I8 = 0, I9 = 0;

  for (uint32_t j = 0; j < 784u; j += 4u) {
    uint4 tv;
    if (USE_THR) {
      tv = *(const uint4*)(trow + j);
    } else {
      const float4 xv = *(const float4*)(xrow + j);
      tv.x = thr_from_x(xv.x);
      tv.y = thr_from_x(xv.y);
      tv.z = thr_from_x(xv.z);
      tv.w = thr_from_x(xv.w);
    }

    const float* w0 = WT + (size_t)(j + 0) * 16;
    const float* w1 = WT + (size_t)(j + 1) * 16;
    const float* w2 = WT + (size_t)(j + 2) * 16;
    const float* w3 = WT + (size_t)(j + 3) * 16;

    uint32_t ba, bb, bc, bd;
    tf_bits4(k0, k1, ks2, cnt0 + j, cnt0 + j + 1u, cnt0 + j + 2u, cnt0 + j + 3u,
             ba, bb, bc, bd);

    const float sa = (ba < tv.x) ? 1.0f : 0.0f;
    const float sb = (bb < tv.y) ? 1.0f : 0.0f;
    const float sc = (bc < tv.z) ? 1.0f : 0.0f;
    const float sd = (bd < tv.w) ? 1.0f : 0.0f;

    I0 += sa * w0[0]; I1 += sa * w0[1]; I2 += sa * w0[2]; I3 += sa * w0[3];
    I4 += sa * w0[4]; I5 += sa * w0[5]; I6 += sa * w0[6]; I7 += sa * w0[7];
    I8 += sa * w0[8]; I9 += sa * w0[9];

    I0 += sb * w1[0]; I1 += sb * w1[1]; I2 += sb * w1[2]; I3 += sb * w1[3];
    I4 += sb * w1[4]; I5 += sb * w1[5]; I6 += sb * w1[6]; I7 += sb * w1[7];
    I8 += sb * w1[8]; I9 += sb * w1[9];

    I0 += sc * w2[0]; I1 += sc * w2[1]; I2 += sc * w2[2]; I3 += sc * w2[3];
    I4 += sc * w2[4]; I5 += sc * w2[5]; I6 += sc * w2[6]; I7 += sc * w2[7];
    I8 += sc * w2[8]; I9 += sc * w2[9];

    I0 += sd * w3[0]; I1 += sd * w3[1]; I2 += sd * w3[2]; I3 += sd * w3[3];
    I4 += sd * w3[4]; I5 += sd * w3[5]; I6 += sd * w3[6]; I7 += sd * w3[7];
    I8 += sd * w3[8]; I9 += sd * w3[9];
  }

  float* dst = Iws + (size_t)task * 10;
  ((float2*)dst)[0] = make_float2(I0, I1);
  ((float2*)dst)[1] = make_float2(I2, I3);
  ((float2*)dst)[2] = make_float2(I4, I5);
  ((float2*)dst)[3] = make_float2(I6, I7);
  ((float2*)dst)[4] = make_float2(I8, I9);
}

// ---------- phase 3: one thread = one (row,o); LIF scan over t ----------
__global__ __launch_bounds__(256)
void snn_phase3(const float* __restrict__ Iws, float* __restrict__ out) {
  const uint32_t id = blockIdx.x * 256u + threadIdx.x;   // < 163,840
  const uint32_t row = id / 10u;
  const uint32_t o = id - row * 10u;
  const float* Ip = Iws + (size_t)row * 1000 + o;
  float v = 0.0f, acc = 0.0f;
  for (int t = 0; t < 100; ++t) {
    const float I = Ip[t * 10];
    const float vv = v + (I - v) * 0.5f;          // exact (x0.5)
    const float s = (vv >= 1.0f) ? 1.0f : 0.0f;
    acc += s;
    v = (1.0f - s) * vv;                          // hard reset
  }
  out[id] = acc / 100.0f;
}

// ---------- fallback (no workspace) ----------
__global__ __launch_bounds__(256, 4)
void snn_fallback(const float* __restrict__ x, const float* __restrict__ W,
                  float* __restrict__ out) {
  __shared__ __align__(16) float Wp[25 * 3 * 32 * 4];
  __shared__ uint32_t keys[100][2];
  const int tid = threadIdx.x;
  for (int s = tid; s < 25 * 3 * 32 * 4; s += 256) {
    int c = s & 3, jl = (s >> 2) & 31, rest = s >> 7;
    int q = rest % 3, jj = rest / 3;
    int o = q * 4 + c, j = jl + 32 * jj;
    float w = 0.0f;
    if (o < 10 && j < 784) w = W[o * 784 + j];
    Wp[s] = w;
  }
  if (tid < 100)
    threefry_full(0u, 42u, 0u, (uint32_t)tid, keys[tid][0], keys[tid][1]);
  __syncthreads();

  const int row = blockIdx.x * 8 + (tid >> 5);
  const int hl = tid & 31;
  const uint32_t cntbase = (uint32_t)row * 784u + (uint32_t)hl;
  const float* xrow = x + (size_t)row * 784;
  float v[10], acc[10];
#pragma unroll
  for (int o = 0; o < 10; ++o) { v[o] = 0.0f; acc[o] = 0.0f; }
  const float4* wq = (const float4*)&Wp[(size_t)hl * 4];

  for (int t = 0; t < 100; ++t) {
    uint32_t k0 = __builtin_amdgcn_readfirstlane(keys[t][0]);
    uint32_t k1 = __builtin_amdgcn_readfirstlane(keys[t][1]);
    uint32_t ks2 = k0 ^ k1 ^ 0x1BD11BDAu;
    float I[10];
#pragma unroll
    for (int o = 0; o < 10; ++o) I[o] = 0.0f;
#pragma unroll 5
    for (int jj = 0; jj < 25; ++jj) {
      const uint32_t bits = tf_bits(k0, k1, ks2, cntbase + (uint32_t)(jj * 32));
      int j = hl + jj * 32;
      float xv = xrow[(j < 784) ? j : 783];
      uint32_t thr = (j < 784) ? thr_from_x(xv) : 0u;
      const float s = (bits < thr) ? 1.0f : 0.0f;
      const float4 wa = wq[jj * 96];
      const float4 wb = wq[jj * 96 + 32];
      const float4 wc = wq[jj * 96 + 64];
      I[0] += s * wa.x; I[1] += s * wa.y; I[2] += s * wa.z; I[3] += s * wa.w;
      I[4] += s * wb.x; I[5] += s * wb.y; I[6] += s * wb.z; I[7] += s * wb.w;
      I[8] += s * wc.x; I[9] += s * wc.y;
    }
#pragma unroll
    for (int o = 0; o < 10; ++o) {
      float r = I[o];
#pragma unroll
      for (int m = 1; m < 32; m <<= 1) r += __shfl_xor(r, m, 32);
      I[o] = r;
    }
#pragma unroll
    for (int o = 0; o < 10; ++o) {
      float vv = v[o] + (I[o] - v[o]) * 0.5f;
      float s = (vv >= 1.0f) ? 1.0f : 0.0f;
      acc[o] += s;
      v[o] = (1.0f - s) * vv;
    }
  }
  if (hl == 0) {
#pragma unroll
    for (int o = 0; o < 10; ++o)
      out[(size_t)row * 10 + o] = acc[o] / 100.0f;
  }
}

extern "C" void kernel_launch(void* const* d_in, const int* in_sizes, int n_in,
                              void* d_out, int out_size, void* d_ws, size_t ws_size,
                              hipStream_t stream) {
  const float* x = (const float*)d_in[0];   // [16384,1,28,28] fp32
  const float* W = (const float*)d_in[1];   // [10,784] fp32
  float* out = (float*)d_out;               // [16384,10] fp32

  const size_t needI  = (size_t)16384 * 100 * 10 * sizeof(float);     // 65.54 MB
  const size_t needWB = (size_t)49 * 2 * 64 * 8 * sizeof(uint16_t);   // 98 KB (16B-mult)
  const size_t needT  = (size_t)16384 * 784 * sizeof(uint32_t);       // 51.38 MB
  const size_t needW  = (size_t)784 * 16 * sizeof(float);             // 50 KB

  if (ws_size >= needI + needWB + needT) {
    // MFMA path
    float* Iws = (float*)d_ws;
    uint16_t* WB = (uint16_t*)((char*)d_ws + needI);
    uint32_t* thr = (uint32_t*)((char*)d_ws + needI + needWB);
    hipLaunchKernelGGL(prep_wb, dim3(25), dim3(256), 0, stream, W, WB);
    hipLaunchKernelGGL(prep_thr, dim3((16384 * 784 + 255) / 256), dim3(256), 0,
                       stream, x, thr);
    hipLaunchKernelGGL(snn_phase1m, dim3(3200), dim3(1024), 0, stream,
                       thr, WB, Iws);
    hipLaunchKernelGGL(snn_phase3, dim3(640), dim3(256), 0, stream, Iws, out);
  } else if (ws_size >= needI + needW) {
    float* Iws = (float*)d_ws;
    float* WT = (float*)((char*)d_ws + needI);
    hipLaunchKernelGGL(prep_wt, dim3((784 * 16 + 255) / 256), dim3(256), 0,
                       stream, W, WT);
    if (ws_size >= needI + needW + needT) {
      uint32_t* thr = (uint32_t*)((char*)d_ws + needI + needW);
      hipLaunchKernelGGL(prep_thr, dim3((16384 * 784 + 255) / 256), dim3(256), 0,
                         stream, x, thr);
      hipLaunchKernelGGL((snn_phase1<true>), dim3(6400), dim3(256), 0, stream,
                         x, thr, WT, Iws);
    } else {
      hipLaunchKernelGGL((snn_phase1<false>), dim3(6400), dim3(256), 0, stream,
                         x, (const uint32_t*)nullptr, WT, Iws);
    }
    hipLaunchKernelGGL(snn_phase3, dim3(640), dim3(256), 0, stream, Iws, out);
  } else {
    hipLaunchKernelGGL(snn_fallback, dim3(2048), dim3(256), 0, stream, x, W, out);
  }
}

// Round 5
// 2330.625 us; speedup vs baseline: 1.0351x; 1.0351x over previous
//
#include <hip/hip_runtime.h>
#include <stdint.h>

#define ROT(x, r) __builtin_rotateleft32((uint32_t)(x), (r))

// Threefry-2x32, 20 rounds
#define TF_G1(x0, x1) \
  x0 += x1; x1 = ROT(x1, 13); x1 ^= x0; \
  x0 += x1; x1 = ROT(x1, 15); x1 ^= x0; \
  x0 += x1; x1 = ROT(x1, 26); x1 ^= x0; \
  x0 += x1; x1 = ROT(x1, 6);  x1 ^= x0;

#define TF_G2(x0, x1) \
  x0 += x1; x1 = ROT(x1, 17); x1 ^= x0; \
  x0 += x1; x1 = ROT(x1, 29); x1 ^= x0; \
  x0 += x1; x1 = ROT(x1, 16); x1 ^= x0; \
  x0 += x1; x1 = ROT(x1, 24); x1 ^= x0;

__device__ __forceinline__ void threefry_full(uint32_t k0, uint32_t k1,
                                              uint32_t c0, uint32_t c1,
                                              uint32_t& o0, uint32_t& o1) {
  uint32_t ks2 = k0 ^ k1 ^ 0x1BD11BDAu;
  uint32_t x0 = c0 + k0, x1 = c1 + k1;
  TF_G1(x0, x1); x0 += k1;  x1 += ks2 + 1u;
  TF_G2(x0, x1); x0 += ks2; x1 += k0 + 2u;
  TF_G1(x0, x1); x0 += k0;  x1 += k1 + 3u;
  TF_G2(x0, x1); x0 += k1;  x1 += ks2 + 4u;
  TF_G1(x0, x1); x0 += ks2; x1 += k0 + 5u;
  o0 = x0; o1 = x1;
}

__device__ __forceinline__ uint32_t tf_bits(uint32_t k0, uint32_t k1, uint32_t ks2,
                                            uint32_t cnt) {
  uint32_t x0 = k0, x1 = cnt + k1;
  TF_G1(x0, x1); x0 += k1;  x1 += ks2 + 1u;
  TF_G2(x0, x1); x0 += ks2; x1 += k0 + 2u;
  TF_G1(x0, x1); x0 += k0;  x1 += k1 + 3u;
  TF_G2(x0, x1); x0 += k1;  x1 += ks2 + 4u;
  TF_G1(x0, x1); x0 += ks2; x1 += k0 + 5u;
  return x0 ^ x1;
}

// ---- 4-stream interleaved threefry (used by fallback scalar path) ----
#define SR4(r) \
  a0 += a1; a1 = ROT(a1, r); a1 ^= a0; \
  b0 += b1; b1 = ROT(b1, r); b1 ^= b0; \
  c0 += c1; c1 = ROT(c1, r); c1 ^= c0; \
  d0 += d1; d1 = ROT(d1, r); d1 ^= d0;

#define INJ4(p, q) \
  a0 += (p); a1 += (q); \
  b0 += (p); b1 += (q); \
  c0 += (p); c1 += (q); \
  d0 += (p); d1 += (q);

__device__ __forceinline__ void tf_bits4(uint32_t k0, uint32_t k1, uint32_t ks2,
                                         uint32_t ca, uint32_t cb, uint32_t cc,
                                         uint32_t cd, uint32_t& ra, uint32_t& rb,
                                         uint32_t& rc, uint32_t& rd) {
  uint32_t a0 = k0, a1 = ca + k1;
  uint32_t b0 = k0, b1 = cb + k1;
  uint32_t c0 = k0, c1 = cc + k1;
  uint32_t d0 = k0, d1 = cd + k1;
  SR4(13) SR4(15) SR4(26) SR4(6)
  INJ4(k1, ks2 + 1u)
  SR4(17) SR4(29) SR4(16) SR4(24)
  INJ4(ks2, k0 + 2u)
  SR4(13) SR4(15) SR4(26) SR4(6)
  INJ4(k0, k1 + 3u)
  SR4(17) SR4(29) SR4(16) SR4(24)
  INJ4(k1, ks2 + 4u)
  SR4(13) SR4(15) SR4(26) SR4(6)
  INJ4(ks2, k0 + 5u)
  ra = a0 ^ a1; rb = b0 ^ b1; rc = c0 ^ c1; rd = d0 ^ d1;
}

// ---- 8-stream interleaved threefry with xad/add3 fused injection seams ----
// Plain middle round: add, rot, xor (3 ops)
#define SR8(r) \
  a0 += a1; a1 = ROT(a1, r); a1 ^= a0; \
  b0 += b1; b1 = ROT(b1, r); b1 ^= b0; \
  c0 += c1; c1 = ROT(c1, r); c1 ^= c0; \
  d0 += d1; d1 = ROT(d1, r); d1 ^= d0; \
  e0 += e1; e1 = ROT(e1, r); e1 ^= e0; \
  f0 += f1; f1 = ROT(f1, r); f1 ^= f0; \
  g0 += g1; g1 = ROT(g1, r); g1 ^= g0; \
  h0 += h1; h1 = ROT(h1, r); h1 ^= h0;

// Injection-closing round: x0 += x1; x1 = (ROT(x1,r) ^ x0) + q
// The trailing "+q" is the x1-injection folded into the round's closing xor
// -> v_xad_u32 ((S0^S1)+S2). x0's injection (+p) is deferred to SRO8.
#define SRI8(r, q) \
  a0 += a1; a1 = (ROT(a1, r) ^ a0) + (q); \
  b0 += b1; b1 = (ROT(b1, r) ^ b0) + (q); \
  c0 += c1; c1 = (ROT(c1, r) ^ c0) + (q); \
  d0 += d1; d1 = (ROT(d1, r) ^ d0) + (q); \
  e0 += e1; e1 = (ROT(e1, r) ^ e0) + (q); \
  f0 += f1; f1 = (ROT(f1, r) ^ f0) + (q); \
  g0 += g1; g1 = (ROT(g1, r) ^ g0) + (q); \
  h0 += h1; h1 = (ROT(h1, r) ^ h0) + (q);

// Opening round after injection: x0 = x0 + p + x1 (v_add3_u32), then rot/xor.
#define SRO8(r, p) \
  a0 = a0 + (p) + a1; a1 = ROT(a1, r) ^ a0; \
  b0 = b0 + (p) + b1; b1 = ROT(b1, r) ^ b0; \
  c0 = c0 + (p) + c1; c1 = ROT(c1, r) ^ c0; \
  d0 = d0 + (p) + d1; d1 = ROT(d1, r) ^ d0; \
  e0 = e0 + (p) + e1; e1 = ROT(e1, r) ^ e0; \
  f0 = f0 + (p) + f1; f1 = ROT(f1, r) ^ f0; \
  g0 = g0 + (p) + g1; g1 = ROT(g1, r) ^ g0; \
  h0 = h0 + (p) + h1; h1 = ROT(h1, r) ^ h0;

// cks = cbase + k1 + 16*s (per-lane); stream e's counter = cbase + 16*s + e.
// Bit-exact re-derivation of 20-round threefry2x32 with:
//   - round-1 add folded into init (x0 = x1 + k0)
//   - +k1 counter fold (cks)
//   - x1-injections fused into closing xor (xad), x0-injections fused into
//     the next round's opening add (add3)
// Injection schedule (after rounds 4/8/12/16/20):
//   (k1, ks2+1) (ks2, k0+2) (k0, k1+3) (k1, ks2+4) (ks2, k0+5)
__device__ __forceinline__ void tf_bits8(uint32_t k0, uint32_t k1, uint32_t ks2,
                                         uint32_t cks,
                                         uint32_t& r0, uint32_t& r1, uint32_t& r2,
                                         uint32_t& r3, uint32_t& r4, uint32_t& r5,
                                         uint32_t& r6, uint32_t& r7) {
  uint32_t a1 = cks;      uint32_t a0 = a1 + k0;
  uint32_t b1 = cks + 1u; uint32_t b0 = b1 + k0;
  uint32_t c1 = cks + 2u; uint32_t c0 = c1 + k0;
  uint32_t d1 = cks + 3u; uint32_t d0 = d1 + k0;
  uint32_t e1 = cks + 4u; uint32_t e0 = e1 + k0;
  uint32_t f1 = cks + 5u; uint32_t f0 = f1 + k0;
  uint32_t g1 = cks + 6u; uint32_t g0 = g1 + k0;
  uint32_t h1 = cks + 7u; uint32_t h0 = h1 + k0;
  // round 1 (its add folded into init): rot13 + xor only
  a1 = ROT(a1, 13) ^ a0;
  b1 = ROT(b1, 13) ^ b0;
  c1 = ROT(c1, 13) ^ c0;
  d1 = ROT(d1, 13) ^ d0;
  e1 = ROT(e1, 13) ^ e0;
  f1 = ROT(f1, 13) ^ f0;
  g1 = ROT(g1, 13) ^ g0;
  h1 = ROT(h1, 13) ^ h0;
  SR8(15) SR8(26)            // rounds 2,3
  SRI8(6,  ks2 + 1u)         // round 4  + x1-inj
  SRO8(17, k1)               // round 5  (x0-inj folded)
  SR8(29) SR8(16)            // rounds 6,7
  SRI8(24, k0 + 2u)          // round 8  + x1-inj
  SRO8(13, ks2)              // round 9
  SR8(15) SR8(26)            // rounds 10,11
  SRI8(6,  k1 + 3u)          // round 12 + x1-inj
  SRO8(17, k0)               // round 13
  SR8(29) SR8(16)            // rounds 14,15
  SRI8(24, ks2 + 4u)         // round 16 + x1-inj
  SRO8(13, k1)               // round 17
  SR8(15) SR8(26)            // rounds 18,19
  SRI8(6,  k0 + 5u)          // round 20 + x1-inj
  // final x0-injection (+ks2) and output fold
  r0 = (a0 + ks2) ^ a1; r1 = (b0 + ks2) ^ b1;
  r2 = (c0 + ks2) ^ c1; r3 = (d0 + ks2) ^ d1;
  r4 = (e0 + ks2) ^ e1; r5 = (f0 + ks2) ^ f1;
  r6 = (g0 + ks2) ^ g1; r7 = (h0 + ks2) ^ h1;
}

typedef __attribute__((ext_vector_type(8))) short bhalf8;   // 8 bf16 (4 VGPR)
typedef __attribute__((ext_vector_type(16))) float fx16;    // 16 f32 acc

static __device__ __forceinline__ uint16_t f2bf_rne(float f) {
  uint32_t u = __float_as_uint(f);
  uint32_t r = (u + 0x7FFFu + ((u >> 16) & 1u)) >> 16;
  return (uint16_t)r;
}

// Exact threshold: u = (bits>>9)*2^-23 < x  <=>  bits>>9 < ceil(x*2^23)
// x*8388608.0f is EXACT in fp32. Saturate at k==2^23: always-spike.
static __device__ __forceinline__ uint32_t thr_from_x(float x) {
  const float xf = x * 8388608.0f;
  uint32_t k = (uint32_t)xf;
  k += ((float)k < xf) ? 1u : 0u;                 // ceil
  return (k >= 8388608u) ? 0xFFFFFFFFu : (k << 9);
}

__global__ __launch_bounds__(256)
void prep_thr(const float* __restrict__ x, uint32_t* __restrict__ thr) {
  int i = blockIdx.x * 256 + threadIdx.x;
  if (i >= 16384 * 784) return;
  thr[i] = thr_from_x(x[i]);
}

// WT[j][0..15]: W[o][j] for o<10, pad 0 — 64 B/row (old scalar-FMA path)
__global__ __launch_bounds__(256)
void prep_wt(const float* __restrict__ W, float* __restrict__ WT) {
  int i = blockIdx.x * 256 + threadIdx.x;
  if (i >= 784 * 16) return;
  int j = i >> 4, o = i & 15;
  WT[i] = (o < 10) ? W[o * 784 + j] : 0.0f;
}

// ---------- split-bf16 B-fragments for mfma_f32_32x32x16_bf16 ----------
// B tile at K-step s (K=16, N=32): lane l holds col = l&31, k = (l>>5)*8 + e.
// Layout: WB[((s*2 + h)*64 + l)*8 + e], h=0 hi, h=1 lo.  49*2*64*8 u16 = 98 KB.
// W = hi + lo (both bf16): products s*hi, s*lo exact (s in {0,1}) -> fp32-class.
__global__ __launch_bounds__(256)
void prep_wb(const float* __restrict__ W, uint16_t* __restrict__ WB) {
  int idx = blockIdx.x * 256 + threadIdx.x;   // (s*2+h)*64 + l
  if (idx >= 49 * 2 * 64) return;
  int l = idx & 63;
  int sh = idx >> 6;
  int h = sh & 1;
  int s = sh >> 1;
  int o = l & 31;
  int kg = l >> 5;
  for (int e = 0; e < 8; ++e) {
    int j = s * 16 + kg * 8 + e;
    float w = (o < 10) ? W[o * 784 + j] : 0.0f;
    uint16_t hi = f2bf_rne(w);
    float whi = __uint_as_float((uint32_t)hi << 16);
    float lo = w - whi;                        // exact residual in fp32
    WB[(size_t)idx * 8 + e] = h ? f2bf_rne(lo) : hi;
  }
}

// ---------- phase 1 (MFMA): one wave = 32 rows x one t; K=784 = 49 x 16 ----
// Round-3 geometry (best measured: 256 thr, 5 waves/EU). Body change:
// xad/add3-fused cipher (~-11% VALU insts/draw).
__global__ __launch_bounds__(256, 5)
void snn_phase1m(const uint32_t* __restrict__ thrg,
                 const uint16_t* __restrict__ WB,
                 float* __restrict__ Iws) {
  const uint32_t wid = (blockIdx.x * 256u + (uint32_t)threadIdx.x) >> 6;  // < 51200
  const uint32_t lane = (uint32_t)threadIdx.x & 63u;
  const uint32_t rowtile = wid / 100u;          // 0..511
  const uint32_t t = wid - rowtile * 100u;      // 0..99
  const uint32_t o = lane & 31u;                // A row / C col within tile
  const uint32_t kg = lane >> 5;                // k-group 0/1
  const uint32_t r = rowtile * 32u + o;         // global batch row

  // per-t step key (matches jax.random.split(key(42),100)[t], partitionable)
  uint32_t k0, k1;
  threefry_full(0u, 42u, 0u, t, k0, k1);
  const uint32_t ks2 = k0 ^ k1 ^ 0x1BD11BDAu;
  const uint32_t cbase = r * 784u + kg * 8u;    // counter/thr base for e=0
  const uint32_t ck = cbase + k1;               // fold +k1 once

  const uint32_t* ta = thrg + cbase;            // 16B-aligned
  const uint16_t* wb = WB + (size_t)lane * 8u;

  fx16 acc;
#pragma unroll
  for (int i = 0; i < 16; ++i) acc[i] = 0.0f;

#pragma unroll 2
  for (uint32_t s = 0; s < 49u; ++s) {
    // thresholds for this lane's 8 draws (2 x dwordx4)
    const uint4 tv0 = *(const uint4*)(ta + (s << 4));
    const uint4 tv1 = *(const uint4*)(ta + (s << 4) + 4u);
    // split-bf16 W fragments (same cachelines for every wave -> L1/L2 hit)
    const bhalf8 bhi = *(const bhalf8*)(wb + (size_t)s * 1024u);
    const bhalf8 blo = *(const bhalf8*)(wb + (size_t)s * 1024u + 512u);

    uint32_t b0, b1, b2, b3, b4, b5, b6, b7;
    tf_bits8(k0, k1, ks2, ck + (s << 4), b0, b1, b2, b3, b4, b5, b6, b7);

    // pack spikes as bf16 {1.0, 0.0} pairs: low half = even k
    union { uint32_t u[4]; bhalf8 v; } A;
    A.u[0] = (b0 < tv0.x ? 0x3F80u : 0u) | (b1 < tv0.y ? 0x3F800000u : 0u);
    A.u[1] = (b2 < tv0.z ? 0x3F80u : 0u) | (b3 < tv0.w ? 0x3F800000u : 0u);
    A.u[2] = (b4 < tv1.x ? 0x3F80u : 0u) | (b5 < tv1.y ? 0x3F800000u : 0u);
    A.u[3] = (b6 < tv1.z ? 0x3F80u : 0u) | (b7 < tv1.w ? 0x3F800000u : 0u);

    acc = __builtin_amdgcn_mfma_f32_32x32x16_bf16(A.v, bhi, acc, 0, 0, 0);
    acc = __builtin_amdgcn_mfma_f32_32x32x16_bf16(A.v, blo, acc, 0, 0, 0);
  }

  // C/D: col = lane&31, row = (reg&3) + 8*(reg>>2) + 4*(lane>>5)  [m74/m101]
  if (o < 10u) {
    float* dst = Iws + (size_t)(rowtile * 32u + kg * 4u) * 1000u + t * 10u + o;
#pragma unroll
    for (int reg = 0; reg < 16; ++reg) {
      const uint32_t row_l = (uint32_t)((reg & 3) + 8 * (reg >> 2));
      dst[(size_t)row_l * 1000u] = acc[reg];
    }
  }
}

// ---------- phase 1 (old scalar-FMA path, kept as ws fallback) ----------
template <bool USE_THR>
__global__ __launch_bounds__(256, 8)
void snn_phase1(const float* __restrict__ x, const uint32_t* __restrict__ thrg,
                const float* __restrict__ WT, float* __restrict__ Iws) {
  const uint32_t task = blockIdx.x * 256u + (uint32_t)threadIdx.x;
  const uint32_t row = task / 100u;
  const uint32_t t = task - row * 100u;

  uint32_t k0, k1;
  threefry_full(0u, 42u, 0u, t, k0, k1);
  const uint32_t ks2 = k0 ^ k1 ^ 0x1BD11BDAu;
  const uint32_t cnt0 = row * 784u;

  const uint32_t* trow = thrg + cnt0;
  const float* xrow = x + cnt0;

  float I0 = 0, I1 = 0, I2 = 0, I3 = 0, I4 = 0,
        I5 = 0, I6 = 0, I7 = 0, I8 = 0, I9 = 0;

  for (uint32_t j = 0; j < 784u; j += 4u) {
    uint4 tv;
    if (USE_THR) {
      tv = *(const uint4*)(trow + j);
    } else {
      const float4 xv = *(const float4*)(xrow + j);
      tv.x = thr_from_x(xv.x);
      tv.y = thr_from_x(xv.y);
      tv.z = thr_from_x(xv.z);
      tv.w = thr_from_x(xv.w);
    }

    const float* w0 = WT + (size_t)(j + 0) * 16;
    const float* w1 = WT + (size_t)(j + 1) * 16;
    const float* w2 = WT + (size_t)(j + 2) * 16;
    const float* w3 = WT + (size_t)(j + 3) * 16;

    uint32_t ba, bb, bc, bd;
    tf_bits4(k0, k1, ks2, cnt0 + j, cnt0 + j + 1u, cnt0 + j + 2u, cnt0 + j + 3u,
             ba, bb, bc, bd);

    const float sa = (ba < tv.x) ? 1.0f : 0.0f;
    const float sb = (bb < tv.y) ? 1.0f : 0.0f;
    const float sc = (bc < tv.z) ? 1.0f : 0.0f;
    const float sd = (bd < tv.w) ? 1.0f : 0.0f;

    I0 += sa * w0[0]; I1 += sa * w0[1]; I2 += sa * w0[2]; I3 += sa * w0[3];
    I4 += sa * w0[4]; I5 += sa * w0[5]; I6 += sa * w0[6]; I7 += sa * w0[7];
    I8 += sa * w0[8]; I9 += sa * w0[9];

    I0 += sb * w1[0]; I1 += sb * w1[1]; I2 += sb * w1[2]; I3 += sb * w1[3];
    I4 += sb * w1[4]; I5 += sb * w1[5]; I6 += sb * w1[6]; I7 += sb * w1[7];
    I8 += sb * w1[8]; I9 += sb * w1[9];

    I0 += sc * w2[0]; I1 += sc * w2[1]; I2 += sc * w2[2]; I3 += sc * w2[3];
    I4 += sc * w2[4]; I5 += sc * w2[5]; I6 += sc * w2[6]; I7 += sc * w2[7];
    I8 += sc * w2[8]; I9 += sc * w2[9];

    I0 += sd * w3[0]; I1 += sd * w3[1]; I2 += sd * w3[2]; I3 += sd * w3[3];
    I4 += sd * w3[4]; I5 += sd * w3[5]; I6 += sd * w3[6]; I7 += sd * w3[7];
    I8 += sd * w3[8]; I9 += sd * w3[9];
  }

  float* dst = Iws + (size_t)task * 10;
  ((float2*)dst)[0] = make_float2(I0, I1);
  ((float2*)dst)[1] = make_float2(I2, I3);
  ((float2*)dst)[2] = make_float2(I4, I5);
  ((float2*)dst)[3] = make_float2(I6, I7);
  ((float2*)dst)[4] = make_float2(I8, I9);
}

// ---------- phase 3: one thread = one (row,o); LIF scan over t ----------
__global__ __launch_bounds__(256)
void snn_phase3(const float* __restrict__ Iws, float* __restrict__ out) {
  const uint32_t id = blockIdx.x * 256u + threadIdx.x;   // < 163,840
  const uint32_t row = id / 10u;
  const uint32_t o = id - row * 10u;
  const float* Ip = Iws + (size_t)row * 1000 + o;
  float v = 0.0f, acc = 0.0f;
  for (int t = 0; t < 100; ++t) {
    const float I = Ip[t * 10];
    const float vv = v + (I - v) * 0.5f;          // exact (x0.5)
    const float s = (vv >= 1.0f) ? 1.0f : 0.0f;
    acc += s;
    v = (1.0f - s) * vv;                          // hard reset
  }
  out[id] = acc / 100.0f;
}

// ---------- fallback (no workspace) ----------
__global__ __launch_bounds__(256, 4)
void snn_fallback(const float* __restrict__ x, const float* __restrict__ W,
                  float* __restrict__ out) {
  __shared__ __align__(16) float Wp[25 * 3 * 32 * 4];
  __shared__ uint32_t keys[100][2];
  const int tid = threadIdx.x;
  for (int s = tid; s < 25 * 3 * 32 * 4; s += 256) {
    int c = s & 3, jl = (s >> 2) & 31, rest = s >> 7;
    int q = rest % 3, jj = rest / 3;
    int o = q * 4 + c, j = jl + 32 * jj;
    float w = 0.0f;
    if (o < 10 && j < 784) w = W[o * 784 + j];
    Wp[s] = w;
  }
  if (tid < 100)
    threefry_full(0u, 42u, 0u, (uint32_t)tid, keys[tid][0], keys[tid][1]);
  __syncthreads();

  const int row = blockIdx.x * 8 + (tid >> 5);
  const int hl = tid & 31;
  const uint32_t cntbase = (uint32_t)row * 784u + (uint32_t)hl;
  const float* xrow = x + (size_t)row * 784;
  float v[10], acc[10];
#pragma unroll
  for (int o = 0; o < 10; ++o) { v[o] = 0.0f; acc[o] = 0.0f; }
  const float4* wq = (const float4*)&Wp[(size_t)hl * 4];

  for (int t = 0; t < 100; ++t) {
    uint32_t k0 = __builtin_amdgcn_readfirstlane(keys[t][0]);
    uint32_t k1 = __builtin_amdgcn_readfirstlane(keys[t][1]);
    uint32_t ks2 = k0 ^ k1 ^ 0x1BD11BDAu;
    float I[10];
#pragma unroll
    for (int o = 0; o < 10; ++o) I[o] = 0.0f;
#pragma unroll 5
    for (int jj = 0; jj < 25; ++jj) {
      const uint32_t bits = tf_bits(k0, k1, ks2, cntbase + (uint32_t)(jj * 32));
      int j = hl + jj * 32;
      float xv = xrow[(j < 784) ? j : 783];
      uint32_t thr = (j < 784) ? thr_from_x(xv) : 0u;
      const float s = (bits < thr) ? 1.0f : 0.0f;
      const float4 wa = wq[jj * 96];
      const float4 wb = wq[jj * 96 + 32];
      const float4 wc = wq[jj * 96 + 64];
      I[0] += s * wa.x; I[1] += s * wa.y; I[2] += s * wa.z; I[3] += s * wa.w;
      I[4] += s * wb.x; I[5] += s * wb.y; I[6] += s * wb.z; I[7] += s * wb.w;
      I[8] += s * wc.x; I[9] += s * wc.y;
    }
#pragma unroll
    for (int o = 0; o < 10; ++o) {
      float r = I[o];
#pragma unroll
      for (int m = 1; m < 32; m <<= 1) r += __shfl_xor(r, m, 32);
      I[o] = r;
    }
#pragma unroll
    for (int o = 0; o < 10; ++o) {
      float vv = v[o] + (I[o] - v[o]) * 0.5f;
      float s = (vv >= 1.0f) ? 1.0f : 0.0f;
      acc[o] += s;
      v[o] = (1.0f - s) * vv;
    }
  }
  if (hl == 0) {
#pragma unroll
    for (int o = 0; o < 10; ++o)
      out[(size_t)row * 10 + o] = acc[o] / 100.0f;
  }
}

extern "C" void kernel_launch(void* const* d_in, const int* in_sizes, int n_in,
                              void* d_out, int out_size, void* d_ws, size_t ws_size,
                              hipStream_t stream) {
  const float* x = (const float*)d_in[0];   // [16384,1,28,28] fp32
  const float* W = (const float*)d_in[1];   // [10,784] fp32
  float* out = (float*)d_out;               // [16384,10] fp32

  const size_t needI  = (size_t)16384 * 100 * 10 * sizeof(float);     // 65.54 MB
  const size_t needWB = (size_t)49 * 2 * 64 * 8 * sizeof(uint16_t);   // 98 KB (16B-mult)
  const size_t needT  = (size_t)16384 * 784 * sizeof(uint32_t);       // 51.38 MB
  const size_t needW  = (size_t)784 * 16 * sizeof(float);             // 50 KB

  if (ws_size >= needI + needWB + needT) {
    // MFMA path
    float* Iws = (float*)d_ws;
    uint16_t* WB = (uint16_t*)((char*)d_ws + needI);
    uint32_t* thr = (uint32_t*)((char*)d_ws + needI + needWB);
    hipLaunchKernelGGL(prep_wb, dim3(25), dim3(256), 0, stream, W, WB);
    hipLaunchKernelGGL(prep_thr, dim3((16384 * 784 + 255) / 256), dim3(256), 0,
                       stream, x, thr);
    hipLaunchKernelGGL(snn_phase1m, dim3(12800), dim3(256), 0, stream,
                       thr, WB, Iws);
    hipLaunchKernelGGL(snn_phase3, dim3(640), dim3(256), 0, stream, Iws, out);
  } else if (ws_size >= needI + needW) {
    float* Iws = (float*)d_ws;
    float* WT = (float*)((char*)d_ws + needI);
    hipLaunchKernelGGL(prep_wt, dim3((784 * 16 + 255) / 256), dim3(256), 0,
                       stream, W, WT);
    if (ws_size >= needI + needW + needT) {
      uint32_t* thr = (uint32_t*)((char*)d_ws + needI + needW);
      hipLaunchKernelGGL(prep_thr, dim3((16384 * 784 + 255) / 256), dim3(256), 0,
                         stream, x, thr);
      hipLaunchKernelGGL((snn_phase1<true>), dim3(6400), dim3(256), 0, stream,
                         x, thr, WT, Iws);
    } else {
      hipLaunchKernelGGL((snn_phase1<false>), dim3(6400), dim3(256), 0, stream,
                         x, (const uint32_t*)nullptr, WT, Iws);
    }
    hipLaunchKernelGGL(snn_phase3, dim3(640), dim3(256), 0, stream, Iws, out);
  } else {
    hipLaunchKernelGGL(snn_fallback, dim3(2048), dim3(256), 0, stream, x, W, out);
  }
}

// Round 6
// 2309.186 us; speedup vs baseline: 1.0447x; 1.0093x over previous
//
#include <hip/hip_runtime.h>
#include <stdint.h>

#define ROT(x, r) __builtin_rotateleft32((uint32_t)(x), (r))

// Threefry-2x32, 20 rounds
#define TF_G1(x0, x1) \
  x0 += x1; x1 = ROT(x1, 13); x1 ^= x0; \
  x0 += x1; x1 = ROT(x1, 15); x1 ^= x0; \
  x0 += x1; x1 = ROT(x1, 26); x1 ^= x0; \
  x0 += x1; x1 = ROT(x1, 6);  x1 ^= x0;

#define TF_G2(x0, x1) \
  x0 += x1; x1 = ROT(x1, 17); x1 ^= x0; \
  x0 += x1; x1 = ROT(x1, 29); x1 ^= x0; \
  x0 += x1; x1 = ROT(x1, 16); x1 ^= x0; \
  x0 += x1; x1 = ROT(x1, 24); x1 ^= x0;

__device__ __forceinline__ void threefry_full(uint32_t k0, uint32_t k1,
                                              uint32_t c0, uint32_t c1,
                                              uint32_t& o0, uint32_t& o1) {
  uint32_t ks2 = k0 ^ k1 ^ 0x1BD11BDAu;
  uint32_t x0 = c0 + k0, x1 = c1 + k1;
  TF_G1(x0, x1); x0 += k1;  x1 += ks2 + 1u;
  TF_G2(x0, x1); x0 += ks2; x1 += k0 + 2u;
  TF_G1(x0, x1); x0 += k0;  x1 += k1 + 3u;
  TF_G2(x0, x1); x0 += k1;  x1 += ks2 + 4u;
  TF_G1(x0, x1); x0 += ks2; x1 += k0 + 5u;
  o0 = x0; o1 = x1;
}

__device__ __forceinline__ uint32_t tf_bits(uint32_t k0, uint32_t k1, uint32_t ks2,
                                            uint32_t cnt) {
  uint32_t x0 = k0, x1 = cnt + k1;
  TF_G1(x0, x1); x0 += k1;  x1 += ks2 + 1u;
  TF_G2(x0, x1); x0 += ks2; x1 += k0 + 2u;
  TF_G1(x0, x1); x0 += k0;  x1 += k1 + 3u;
  TF_G2(x0, x1); x0 += k1;  x1 += ks2 + 4u;
  TF_G1(x0, x1); x0 += ks2; x1 += k0 + 5u;
  return x0 ^ x1;
}

// ---- 4-stream interleaved threefry (used by fallback scalar path) ----
#define SR4(r) \
  a0 += a1; a1 = ROT(a1, r); a1 ^= a0; \
  b0 += b1; b1 = ROT(b1, r); b1 ^= b0; \
  c0 += c1; c1 = ROT(c1, r); c1 ^= c0; \
  d0 += d1; d1 = ROT(d1, r); d1 ^= d0;

#define INJ4(p, q) \
  a0 += (p); a1 += (q); \
  b0 += (p); b1 += (q); \
  c0 += (p); c1 += (q); \
  d0 += (p); d1 += (q);

__device__ __forceinline__ void tf_bits4(uint32_t k0, uint32_t k1, uint32_t ks2,
                                         uint32_t ca, uint32_t cb, uint32_t cc,
                                         uint32_t cd, uint32_t& ra, uint32_t& rb,
                                         uint32_t& rc, uint32_t& rd) {
  uint32_t a0 = k0, a1 = ca + k1;
  uint32_t b0 = k0, b1 = cb + k1;
  uint32_t c0 = k0, c1 = cc + k1;
  uint32_t d0 = k0, d1 = cd + k1;
  SR4(13) SR4(15) SR4(26) SR4(6)
  INJ4(k1, ks2 + 1u)
  SR4(17) SR4(29) SR4(16) SR4(24)
  INJ4(ks2, k0 + 2u)
  SR4(13) SR4(15) SR4(26) SR4(6)
  INJ4(k0, k1 + 3u)
  SR4(17) SR4(29) SR4(16) SR4(24)
  INJ4(k1, ks2 + 4u)
  SR4(13) SR4(15) SR4(26) SR4(6)
  INJ4(ks2, k0 + 5u)
  ra = a0 ^ a1; rb = b0 ^ b1; rc = c0 ^ c1; rd = d0 ^ d1;
}

// ---- 8-stream interleaved threefry with xad/add3 fused injection seams ----
#define SR8(r) \
  a0 += a1; a1 = ROT(a1, r); a1 ^= a0; \
  b0 += b1; b1 = ROT(b1, r); b1 ^= b0; \
  c0 += c1; c1 = ROT(c1, r); c1 ^= c0; \
  d0 += d1; d1 = ROT(d1, r); d1 ^= d0; \
  e0 += e1; e1 = ROT(e1, r); e1 ^= e0; \
  f0 += f1; f1 = ROT(f1, r); f1 ^= f0; \
  g0 += g1; g1 = ROT(g1, r); g1 ^= g0; \
  h0 += h1; h1 = ROT(h1, r); h1 ^= h0;

#define SRI8(r, q) \
  a0 += a1; a1 = (ROT(a1, r) ^ a0) + (q); \
  b0 += b1; b1 = (ROT(b1, r) ^ b0) + (q); \
  c0 += c1; c1 = (ROT(c1, r) ^ c0) + (q); \
  d0 += d1; d1 = (ROT(d1, r) ^ d0) + (q); \
  e0 += e1; e1 = (ROT(e1, r) ^ e0) + (q); \
  f0 += f1; f1 = (ROT(f1, r) ^ f0) + (q); \
  g0 += g1; g1 = (ROT(g1, r) ^ g0) + (q); \
  h0 += h1; h1 = (ROT(h1, r) ^ h0) + (q);

#define SRO8(r, p) \
  a0 = a0 + (p) + a1; a1 = ROT(a1, r) ^ a0; \
  b0 = b0 + (p) + b1; b1 = ROT(b1, r) ^ b0; \
  c0 = c0 + (p) + c1; c1 = ROT(c1, r) ^ c0; \
  d0 = d0 + (p) + d1; d1 = ROT(d1, r) ^ d0; \
  e0 = e0 + (p) + e1; e1 = ROT(e1, r) ^ e0; \
  f0 = f0 + (p) + f1; f1 = ROT(f1, r) ^ f0; \
  g0 = g0 + (p) + g1; g1 = ROT(g1, r) ^ g0; \
  h0 = h0 + (p) + h1; h1 = ROT(h1, r) ^ h0;

// Bit-exact 20-round threefry2x32 (partitionable-JAX schedule), fused seams.
__device__ __forceinline__ void tf_bits8(uint32_t k0, uint32_t k1, uint32_t ks2,
                                         uint32_t cks,
                                         uint32_t& r0, uint32_t& r1, uint32_t& r2,
                                         uint32_t& r3, uint32_t& r4, uint32_t& r5,
                                         uint32_t& r6, uint32_t& r7) {
  uint32_t a1 = cks;      uint32_t a0 = a1 + k0;
  uint32_t b1 = cks + 1u; uint32_t b0 = b1 + k0;
  uint32_t c1 = cks + 2u; uint32_t c0 = c1 + k0;
  uint32_t d1 = cks + 3u; uint32_t d0 = d1 + k0;
  uint32_t e1 = cks + 4u; uint32_t e0 = e1 + k0;
  uint32_t f1 = cks + 5u; uint32_t f0 = f1 + k0;
  uint32_t g1 = cks + 6u; uint32_t g0 = g1 + k0;
  uint32_t h1 = cks + 7u; uint32_t h0 = h1 + k0;
  a1 = ROT(a1, 13) ^ a0;
  b1 = ROT(b1, 13) ^ b0;
  c1 = ROT(c1, 13) ^ c0;
  d1 = ROT(d1, 13) ^ d0;
  e1 = ROT(e1, 13) ^ e0;
  f1 = ROT(f1, 13) ^ f0;
  g1 = ROT(g1, 13) ^ g0;
  h1 = ROT(h1, 13) ^ h0;
  SR8(15) SR8(26)            // rounds 2,3
  SRI8(6,  ks2 + 1u)         // round 4  + x1-inj
  SRO8(17, k1)               // round 5
  SR8(29) SR8(16)            // rounds 6,7
  SRI8(24, k0 + 2u)          // round 8
  SRO8(13, ks2)              // round 9
  SR8(15) SR8(26)            // rounds 10,11
  SRI8(6,  k1 + 3u)          // round 12
  SRO8(17, k0)               // round 13
  SR8(29) SR8(16)            // rounds 14,15
  SRI8(24, ks2 + 4u)         // round 16
  SRO8(13, k1)               // round 17
  SR8(15) SR8(26)            // rounds 18,19
  SRI8(6,  k0 + 5u)          // round 20
  r0 = (a0 + ks2) ^ a1; r1 = (b0 + ks2) ^ b1;
  r2 = (c0 + ks2) ^ c1; r3 = (d0 + ks2) ^ d1;
  r4 = (e0 + ks2) ^ e1; r5 = (f0 + ks2) ^ f1;
  r6 = (g0 + ks2) ^ g1; r7 = (h0 + ks2) ^ h1;
}

typedef __attribute__((ext_vector_type(8))) short bhalf8;   // 8 bf16 (4 VGPR)
typedef __attribute__((ext_vector_type(16))) float fx16;    // 16 f32 acc

static __device__ __forceinline__ uint16_t f2bf_rne(float f) {
  uint32_t u = __float_as_uint(f);
  uint32_t r = (u + 0x7FFFu + ((u >> 16) & 1u)) >> 16;
  return (uint16_t)r;
}

// Exact threshold: u = (bits>>9)*2^-23 < x  <=>  bits>>9 < ceil(x*2^23)
// x*8388608.0f is EXACT in fp32. Saturate at k==2^23: always-spike.
static __device__ __forceinline__ uint32_t thr_from_x(float x) {
  const float xf = x * 8388608.0f;
  uint32_t k = (uint32_t)xf;
  k += ((float)k < xf) ? 1u : 0u;                 // ceil
  return (k >= 8388608u) ? 0xFFFFFFFFu : (k << 9);
}

// linear thr (fallback scalar path)
__global__ __launch_bounds__(256)
void prep_thr(const float* __restrict__ x, uint32_t* __restrict__ thr) {
  int i = blockIdx.x * 256 + threadIdx.x;
  if (i >= 16384 * 784) return;
  thr[i] = thr_from_x(x[i]);
}

// ---- transposed thr for the MFMA path: thrT[rt][s][h][lane][e] ----
// Wave (rowtile rt) at K-step s loads tv0/tv1 as contiguous 1KB segments
// (fully coalesced) instead of 64-line-split row-strided dwordx4.
// Element (rt,s,h,lane,e) = thr_from_x( x[r*784 + j] ),
//   r = rt*32 + (lane&31), kg = lane>>5, j = s*16 + kg*8 + h*4 + e.
__global__ __launch_bounds__(256)
void prep_thr2(const float* __restrict__ x, uint32_t* __restrict__ thrT) {
  int i = blockIdx.x * 256 + threadIdx.x;
  if (i >= 512 * 49 * 2 * 64 * 4) return;       // 12,845,056
  const int e = i & 3;
  const int lane = (i >> 2) & 63;
  const int h = (i >> 8) & 1;
  const int rest = i >> 9;
  const int s = rest % 49;
  const int rt = rest / 49;
  const int r = rt * 32 + (lane & 31);
  const int kg = lane >> 5;
  const int j = s * 16 + kg * 8 + h * 4 + e;
  thrT[i] = thr_from_x(x[r * 784 + j]);
}

// WT[j][0..15]: W[o][j] for o<10, pad 0 — 64 B/row (old scalar-FMA path)
__global__ __launch_bounds__(256)
void prep_wt(const float* __restrict__ W, float* __restrict__ WT) {
  int i = blockIdx.x * 256 + threadIdx.x;
  if (i >= 784 * 16) return;
  int j = i >> 4, o = i & 15;
  WT[i] = (o < 10) ? W[o * 784 + j] : 0.0f;
}

// ---------- split-bf16 B-fragments for mfma_f32_32x32x16_bf16 ----------
__global__ __launch_bounds__(256)
void prep_wb(const float* __restrict__ W, uint16_t* __restrict__ WB) {
  int idx = blockIdx.x * 256 + threadIdx.x;   // (s*2+h)*64 + l
  if (idx >= 49 * 2 * 64) return;
  int l = idx & 63;
  int sh = idx >> 6;
  int h = sh & 1;
  int s = sh >> 1;
  int o = l & 31;
  int kg = l >> 5;
  for (int e = 0; e < 8; ++e) {
    int j = s * 16 + kg * 8 + e;
    float w = (o < 10) ? W[o * 784 + j] : 0.0f;
    uint16_t hi = f2bf_rne(w);
    float whi = __uint_as_float((uint32_t)hi << 16);
    float lo = w - whi;                        // exact residual in fp32
    WB[(size_t)idx * 8 + e] = h ? f2bf_rne(lo) : hi;
  }
}

// ---------- phase 1 (MFMA): one wave = 32 rows x one t; K=784 = 49 x 16 ----
// Round-5 body; single change: coalesced transposed-thr loads.
__global__ __launch_bounds__(256, 5)
void snn_phase1m(const uint32_t* __restrict__ thrT,
                 const uint16_t* __restrict__ WB,
                 float* __restrict__ Iws) {
  const uint32_t wid = (blockIdx.x * 256u + (uint32_t)threadIdx.x) >> 6;  // < 51200
  const uint32_t lane = (uint32_t)threadIdx.x & 63u;
  const uint32_t rowtile = wid / 100u;          // 0..511
  const uint32_t t = wid - rowtile * 100u;      // 0..99
  const uint32_t o = lane & 31u;                // A row / C col within tile
  const uint32_t kg = lane >> 5;                // k-group 0/1
  const uint32_t r = rowtile * 32u + o;         // global batch row

  // per-t step key (matches jax.random.split(key(42),100)[t], partitionable)
  uint32_t k0, k1;
  threefry_full(0u, 42u, 0u, t, k0, k1);
  const uint32_t ks2 = k0 ^ k1 ^ 0x1BD11BDAu;
  const uint32_t cbase = r * 784u + kg * 8u;    // counter base for e=0
  const uint32_t ck = cbase + k1;               // fold +k1 once

  // coalesced transposed thresholds: lanes 0..63 -> contiguous 1KB
  const uint32_t* tb = thrT + (size_t)rowtile * (49u * 512u) + lane * 4u;
  const uint16_t* wb = WB + (size_t)lane * 8u;

  fx16 acc;
#pragma unroll
  for (int i = 0; i < 16; ++i) acc[i] = 0.0f;

#pragma unroll 2
  for (uint32_t s = 0; s < 49u; ++s) {
    // thresholds for this lane's 8 draws (2 x dwordx4, coalesced)
    const uint4 tv0 = *(const uint4*)(tb + (size_t)s * 512u);
    const uint4 tv1 = *(const uint4*)(tb + (size_t)s * 512u + 256u);
    // split-bf16 W fragments (coalesced, L1/L2-resident)
    const bhalf8 bhi = *(const bhalf8*)(wb + (size_t)s * 1024u);
    const bhalf8 blo = *(const bhalf8*)(wb + (size_t)s * 1024u + 512u);

    uint32_t b0, b1, b2, b3, b4, b5, b6, b7;
    tf_bits8(k0, k1, ks2, ck + (s << 4), b0, b1, b2, b3, b4, b5, b6, b7);

    // pack spikes as bf16 {1.0, 0.0} pairs: low half = even k
    union { uint32_t u[4]; bhalf8 v; } A;
    A.u[0] = (b0 < tv0.x ? 0x3F80u : 0u) | (b1 < tv0.y ? 0x3F800000u : 0u);
    A.u[1] = (b2 < tv0.z ? 0x3F80u : 0u) | (b3 < tv0.w ? 0x3F800000u : 0u);
    A.u[2] = (b4 < tv1.x ? 0x3F80u : 0u) | (b5 < tv1.y ? 0x3F800000u : 0u);
    A.u[3] = (b6 < tv1.z ? 0x3F80u : 0u) | (b7 < tv1.w ? 0x3F800000u : 0u);

    acc = __builtin_amdgcn_mfma_f32_32x32x16_bf16(A.v, bhi, acc, 0, 0, 0);
    acc = __builtin_amdgcn_mfma_f32_32x32x16_bf16(A.v, blo, acc, 0, 0, 0);
  }

  // C/D: col = lane&31, row = (reg&3) + 8*(reg>>2) + 4*(lane>>5)  [m74/m101]
  if (o < 10u) {
    float* dst = Iws + (size_t)(rowtile * 32u + kg * 4u) * 1000u + t * 10u + o;
#pragma unroll
    for (int reg = 0; reg < 16; ++reg) {
      const uint32_t row_l = (uint32_t)((reg & 3) + 8 * (reg >> 2));
      dst[(size_t)row_l * 1000u] = acc[reg];
    }
  }
}

// ---------- phase 1 (old scalar-FMA path, kept as ws fallback) ----------
template <bool USE_THR>
__global__ __launch_bounds__(256, 8)
void snn_phase1(const float* __restrict__ x, const uint32_t* __restrict__ thrg,
                const float* __restrict__ WT, float* __restrict__ Iws) {
  const uint32_t task = blockIdx.x * 256u + (uint32_t)threadIdx.x;
  const uint32_t row = task / 100u;
  const uint32_t t = task - row * 100u;

  uint32_t k0, k1;
  threefry_full(0u, 42u, 0u, t, k0, k1);
  const uint32_t ks2 = k0 ^ k1 ^ 0x1BD11BDAu;
  const uint32_t cnt0 = row * 784u;

  const uint32_t* trow = thrg + cnt0;
  const float* xrow = x + cnt0;

  float I0 = 0, I1 = 0, I2 = 0, I3 = 0, I4 = 0,
        I5 = 0, I6 = 0, I7 = 0, I8 = 0, I9 = 0;

  for (uint32_t j = 0; j < 784u; j += 4u) {
    uint4 tv;
    if (USE_THR) {
      tv = *(const uint4*)(trow + j);
    } else {
      const float4 xv = *(const float4*)(xrow + j);
      tv.x = thr_from_x(xv.x);
      tv.y = thr_from_x(xv.y);
      tv.z = thr_from_x(xv.z);
      tv.w = thr_from_x(xv.w);
    }

    const float* w0 = WT + (size_t)(j + 0) * 16;
    const float* w1 = WT + (size_t)(j + 1) * 16;
    const float* w2 = WT + (size_t)(j + 2) * 16;
    const float* w3 = WT + (size_t)(j + 3) * 16;

    uint32_t ba, bb, bc, bd;
    tf_bits4(k0, k1, ks2, cnt0 + j, cnt0 + j + 1u, cnt0 + j + 2u, cnt0 + j + 3u,
             ba, bb, bc, bd);

    const float sa = (ba < tv.x) ? 1.0f : 0.0f;
    const float sb = (bb < tv.y) ? 1.0f : 0.0f;
    const float sc = (bc < tv.z) ? 1.0f : 0.0f;
    const float sd = (bd < tv.w) ? 1.0f : 0.0f;

    I0 += sa * w0[0]; I1 += sa * w0[1]; I2 += sa * w0[2]; I3 += sa * w0[3];
    I4 += sa * w0[4]; I5 += sa * w0[5]; I6 += sa * w0[6]; I7 += sa * w0[7];
    I8 += sa * w0[8]; I9 += sa * w0[9];

    I0 += sb * w1[0]; I1 += sb * w1[1]; I2 += sb * w1[2]; I3 += sb * w1[3];
    I4 += sb * w1[4]; I5 += sb * w1[5]; I6 += sb * w1[6]; I7 += sb * w1[7];
    I8 += sb * w1[8]; I9 += sb * w1[9];

    I0 += sc * w2[0]; I1 += sc * w2[1]; I2 += sc * w2[2]; I3 += sc * w2[3];
    I4 += sc * w2[4]; I5 += sc * w2[5]; I6 += sc * w2[6]; I7 += sc * w2[7];
    I8 += sc * w2[8]; I9 += sc * w2[9];

    I0 += sd * w3[0]; I1 += sd * w3[1]; I2 += sd * w3[2]; I3 += sd * w3[3];
    I4 += sd * w3[4]; I5 += sd * w3[5]; I6 += sd * w3[6]; I7 += sd * w3[7];
    I8 += sd * w3[8]; I9 += sd * w3[9];
  }

  float* dst = Iws + (size_t)task * 10;
  ((float2*)dst)[0] = make_float2(I0, I1);
  ((float2*)dst)[1] = make_float2(I2, I3);
  ((float2*)dst)[2] = make_float2(I4, I5);
  ((float2*)dst)[3] = make_float2(I6, I7);
  ((float2*)dst)[4] = make_float2(I8, I9);
}

// ---------- phase 3: one thread = one (row,o); LIF scan over t ----------
__global__ __launch_bounds__(256)
void snn_phase3(const float* __restrict__ Iws, float* __restrict__ out) {
  const uint32_t id = blockIdx.x * 256u + threadIdx.x;   // < 163,840
  const uint32_t row = id / 10u;
  const uint32_t o = id - row * 10u;
  const float* Ip = Iws + (size_t)row * 1000 + o;
  float v = 0.0f, acc = 0.0f;
  for (int t = 0; t < 100; ++t) {
    const float I = Ip[t * 10];
    const float vv = v + (I - v) * 0.5f;          // exact (x0.5)
    const float s = (vv >= 1.0f) ? 1.0f : 0.0f;
    acc += s;
    v = (1.0f - s) * vv;                          // hard reset
  }
  out[id] = acc / 100.0f;
}

// ---------- fallback (no workspace) ----------
__global__ __launch_bounds__(256, 4)
void snn_fallback(const float* __restrict__ x, const float* __restrict__ W,
                  float* __restrict__ out) {
  __shared__ __align__(16) float Wp[25 * 3 * 32 * 4];
  __shared__ uint32_t keys[100][2];
  const int tid = threadIdx.x;
  for (int s = tid; s < 25 * 3 * 32 * 4; s += 256) {
    int c = s & 3, jl = (s >> 2) & 31, rest = s >> 7;
    int q = rest % 3, jj = rest / 3;
    int o = q * 4 + c, j = jl + 32 * jj;
    float w = 0.0f;
    if (o < 10 && j < 784) w = W[o * 784 + j];
    Wp[s] = w;
  }
  if (tid < 100)
    threefry_full(0u, 42u, 0u, (uint32_t)tid, keys[tid][0], keys[tid][1]);
  __syncthreads();

  const int row = blockIdx.x * 8 + (tid >> 5);
  const int hl = tid & 31;
  const uint32_t cntbase = (uint32_t)row * 784u + (uint32_t)hl;
  const float* xrow = x + (size_t)row * 784;
  float v[10], acc[10];
#pragma unroll
  for (int o = 0; o < 10; ++o) { v[o] = 0.0f; acc[o] = 0.0f; }
  const float4* wq = (const float4*)&Wp[(size_t)hl * 4];

  for (int t = 0; t < 100; ++t) {
    uint32_t k0 = __builtin_amdgcn_readfirstlane(keys[t][0]);
    uint32_t k1 = __builtin_amdgcn_readfirstlane(keys[t][1]);
    uint32_t ks2 = k0 ^ k1 ^ 0x1BD11BDAu;
    float I[10];
#pragma unroll
    for (int o = 0; o < 10; ++o) I[o] = 0.0f;
#pragma unroll 5
    for (int jj = 0; jj < 25; ++jj) {
      const uint32_t bits = tf_bits(k0, k1, ks2, cntbase + (uint32_t)(jj * 32));
      int j = hl + jj * 32;
      float xv = xrow[(j < 784) ? j : 783];
      uint32_t thr = (j < 784) ? thr_from_x(xv) : 0u;
      const float s = (bits < thr) ? 1.0f : 0.0f;
      const float4 wa = wq[jj * 96];
      const float4 wb = wq[jj * 96 + 32];
      const float4 wc = wq[jj * 96 + 64];
      I[0] += s * wa.x; I[1] += s * wa.y; I[2] += s * wa.z; I[3] += s * wa.w;
      I[4] += s * wb.x; I[5] += s * wb.y; I[6] += s * wb.z; I[7] += s * wb.w;
      I[8] += s * wc.x; I[9] += s * wc.y;
    }
#pragma unroll
    for (int o = 0; o < 10; ++o) {
      float r = I[o];
#pragma unroll
      for (int m = 1; m < 32; m <<= 1) r += __shfl_xor(r, m, 32);
      I[o] = r;
    }
#pragma unroll
    for (int o = 0; o < 10; ++o) {
      float vv = v[o] + (I[o] - v[o]) * 0.5f;
      float s = (vv >= 1.0f) ? 1.0f : 0.0f;
      acc[o] += s;
      v[o] = (1.0f - s) * vv;
    }
  }
  if (hl == 0) {
#pragma unroll
    for (int o = 0; o < 10; ++o)
      out[(size_t)row * 10 + o] = acc[o] / 100.0f;
  }
}

extern "C" void kernel_launch(void* const* d_in, const int* in_sizes, int n_in,
                              void* d_out, int out_size, void* d_ws, size_t ws_size,
                              hipStream_t stream) {
  const float* x = (const float*)d_in[0];   // [16384,1,28,28] fp32
  const float* W = (const float*)d_in[1];   // [10,784] fp32
  float* out = (float*)d_out;               // [16384,10] fp32

  const size_t needI  = (size_t)16384 * 100 * 10 * sizeof(float);     // 65.54 MB
  const size_t needWB = (size_t)49 * 2 * 64 * 8 * sizeof(uint16_t);   // 98 KB (16B-mult)
  const size_t needT  = (size_t)16384 * 784 * sizeof(uint32_t);       // 51.38 MB
  const size_t needW  = (size_t)784 * 16 * sizeof(float);             // 50 KB

  if (ws_size >= needI + needWB + needT) {
    // MFMA path (transposed thr)
    float* Iws = (float*)d_ws;
    uint16_t* WB = (uint16_t*)((char*)d_ws + needI);
    uint32_t* thrT = (uint32_t*)((char*)d_ws + needI + needWB);
    hipLaunchKernelGGL(prep_wb, dim3(25), dim3(256), 0, stream, W, WB);
    hipLaunchKernelGGL(prep_thr2, dim3((512 * 49 * 2 * 64 * 4 + 255) / 256),
                       dim3(256), 0, stream, x, thrT);
    hipLaunchKernelGGL(snn_phase1m, dim3(12800), dim3(256), 0, stream,
                       thrT, WB, Iws);
    hipLaunchKernelGGL(snn_phase3, dim3(640), dim3(256), 0, stream, Iws, out);
  } else if (ws_size >= needI + needW) {
    float* Iws = (float*)d_ws;
    float* WT = (float*)((char*)d_ws + needI);
    hipLaunchKernelGGL(prep_wt, dim3((784 * 16 + 255) / 256), dim3(256), 0,
                       stream, W, WT);
    if (ws_size >= needI + needW + needT) {
      uint32_t* thr = (uint32_t*)((char*)d_ws + needI + needW);
      hipLaunchKernelGGL(prep_thr, dim3((16384 * 784 + 255) / 256), dim3(256), 0,
                         stream, x, thr);
      hipLaunchKernelGGL((snn_phase1<true>), dim3(6400), dim3(256), 0, stream,
                         x, thr, WT, Iws);
    } else {
      hipLaunchKernelGGL((snn_phase1<false>), dim3(6400), dim3(256), 0, stream,
                         x, (const uint32_t*)nullptr, WT, Iws);
    }
    hipLaunchKernelGGL(snn_phase3, dim3(640), dim3(256), 0, stream, Iws, out);
  } else {
    hipLaunchKernelGGL(snn_fallback, dim3(2048), dim3(256), 0, stream, x, W, out);
  }
}